// Round 1
// baseline (111.100 us; speedup 1.0000x reference)
//
#include <hip/hip_runtime.h>
#include <math.h>

#define NN 384
#define IN_F 64
#define OUT_F 4
#define HID 32
#define RR 16
#define HP_W 1024   // 2*R*HID
#define EPSF 1e-5f

// ---------------- kernel 1: hp[m][j] = sum_k h[m][k] * W_fc[j][k] ----------------
__global__ __launch_bounds__(256) void k_hp(const float* __restrict__ h,
                                            const float* __restrict__ Wfc,
                                            float* __restrict__ hp) {
    int m = blockIdx.x;
    __shared__ float4 hs4[IN_F / 4];
    int tid = threadIdx.x;
    if (tid < IN_F / 4) hs4[tid] = ((const float4*)(h + m * IN_F))[tid];
    __syncthreads();
    const float4* W4 = (const float4*)Wfc;
    for (int jj = 0; jj < 4; ++jj) {
        int j = tid + 256 * jj;
        const float4* row = W4 + (size_t)j * (IN_F / 4);
        float acc = 0.f;
#pragma unroll
        for (int k = 0; k < IN_F / 4; ++k) {
            float4 w = row[k];
            float4 hv = hs4[k];
            acc += w.x * hv.x + w.y * hv.y + w.z * hv.z + w.w * hv.w;
        }
        hp[(size_t)m * HP_W + j] = acc;
    }
}

// ---------------- kernel 2: per-m reduction -> outv[m][128] ----------------
// bk[c,b] = sum_r hpK[m,r,c]*S[r,b] + sum_n dxn[n,b]*P_K[n,c]
//   S[r,b]   = sum_n smear[n,r]*dxn[n,b]            (shared between K and Q)
//   P_K[n,c] = sum_r smear[n,r]*hpK[n,r,c]
__global__ __launch_bounds__(256) void k_mid(const float* __restrict__ x,
                                             const float* __restrict__ hp,
                                             const float* __restrict__ Wsum,
                                             const float* __restrict__ bsum,
                                             float* __restrict__ outv,
                                             float beta, float start) {
    const int m = blockIdx.x;
    const int tid = threadIdx.x;

    __shared__ float hp_m[HP_W];        // 4 KB
    __shared__ float hp_n[8 * HP_W];    // 32 KB
    __shared__ float smear_s[8][16];
    __shared__ float dxn_s[8][4];
    __shared__ float P_s[8][64];
    __shared__ float S_s[16][3];
    __shared__ float bkq_s[2][HID][3];
    __shared__ float silu_s[HID];

    for (int i = tid; i < HP_W; i += 256) hp_m[i] = hp[(size_t)m * HP_W + i];
    const float xm0 = x[m * 3 + 0], xm1 = x[m * 3 + 1], xm2 = x[m * 3 + 2];

    // thread roles for the accumulate phase
    const int kq = tid / 96;            // 0:K 1:Q   (valid tid<192)
    const int rem = tid % 96;
    const int bb = rem / 32;            // 0..2
    const int cc = rem % 32;            // 0..31
    const int sidx = tid - 192;         // 0..47 for S-threads
    const int sr = sidx / 3, sb = sidx % 3;

    float accU = 0.f;
    float accS = 0.f;

    for (int t = 0; t < NN / 8; ++t) {
        const int n0 = t * 8;
        __syncthreads();  // protect previous tile's shared reads
        // stage hp rows n0..n0+7 (coalesced float4)
        {
            const float4* src = (const float4*)(hp + (size_t)n0 * HP_W);
            float4* dst = (float4*)hp_n;
#pragma unroll
            for (int i = 0; i < 8; ++i) dst[tid + 256 * i] = src[tid + 256 * i];
        }
        // geometry: threads 0..127 -> (ni, r)
        if (tid < 128) {
            const int ni = tid >> 4, r = tid & 15;
            const int n = n0 + ni;
            float d0 = xm0 - x[n * 3 + 0];
            float d1 = xm1 - x[n * 3 + 1];
            float d2 = xm2 - x[n * 3 + 2];
            float nsq = d0 * d0 + d1 * d1 + d2 * d2 + EPSF;
            float dist = sqrtf(nsq);
            float cut = (dist < 5.0f) ? 0.5f * (__cosf(dist * 0.62831853071795864769f) + 1.0f) : 0.0f;
            float en = __expf(-dist);
            float mean_r = start + (1.0f - start) * ((float)r * (1.0f / 15.0f));
            float dmr = en - mean_r;
            smear_s[ni][r] = cut * __expf(-beta * dmr * dmr);
            if (r < 3) {
                float dv = (r == 0) ? d0 : (r == 1 ? d1 : d2);
                dxn_s[ni][r] = dv / nsq;
            }
        }
        __syncthreads();
        // P phase: 8 ni * 64 (kq,c) = 512 items, 2 per thread
#pragma unroll
        for (int it = 0; it < 2; ++it) {
            const int item = tid + it * 256;
            const int ni = item >> 6;
            const int c6 = item & 63;                 // kq*32 + c
            const float* base = hp_n + ni * HP_W + (c6 >> 5) * 512 + (c6 & 31);
            const float* sm = smear_s[ni];
            float p = 0.f;
#pragma unroll
            for (int r = 0; r < 16; ++r) p += sm[r] * base[r * 32];
            P_s[ni][c6] = p;
        }
        __syncthreads();
        // accumulate
        if (tid < 192) {
#pragma unroll
            for (int ni = 0; ni < 8; ++ni)
                accU += dxn_s[ni][bb] * P_s[ni][kq * 32 + cc];
        } else if (tid < 240) {
#pragma unroll
            for (int ni = 0; ni < 8; ++ni)
                accS += smear_s[ni][sr] * dxn_s[ni][sb];
        }
    }
    __syncthreads();
    if (tid >= 192 && tid < 240) S_s[sr][sb] = accS;
    __syncthreads();
    if (tid < 192) {
        float v = accU;
        const float* hb = hp_m + kq * 512 + cc;
#pragma unroll
        for (int r = 0; r < 16; ++r) v += hb[r * 32] * S_s[r][bb];
        bkq_s[kq][cc][bb] = v;
    }
    __syncthreads();
    if (tid < HID) {
        float a = bkq_s[0][tid][0] * bkq_s[1][tid][0]
                + bkq_s[0][tid][1] * bkq_s[1][tid][1]
                + bkq_s[0][tid][2] * bkq_s[1][tid][2];
        float sg = 1.0f / (1.0f + __expf(-a));
        silu_s[tid] = a * sg;
    }
    __syncthreads();
    if (tid < 128) {
        float acc = bsum[tid];
        const float* wr = Wsum + tid * HID;
#pragma unroll
        for (int c = 0; c < HID; ++c) acc += wr[c] * silu_s[c];
        outv[(size_t)m * 128 + tid] = acc;
    }
}

// ---------------- kernel 3: K2/Q2 expansion ----------------
// out row of 128 = [16 r][8 o]; K2 takes o 0..3 (float4 idx 2r), Q2 o 4..7 (2r+1)
__global__ __launch_bounds__(256) void k_expand(const float* __restrict__ outv,
                                                float* __restrict__ out) {
    const int bid = blockIdx.x;
    const int m = bid / 24;
    const int n0 = (bid % 24) * 16;
    const int tid = threadIdx.x;
    __shared__ float4 om[32];
    if (tid < 32) om[tid] = ((const float4*)(outv + (size_t)m * 128))[tid];
    __syncthreads();
    const int ni = tid >> 4;
    const int r = tid & 15;
    const int n = n0 + ni;
    const float4* on = (const float4*)(outv + (size_t)n * 128);
    float4 a0 = om[2 * r], a1 = om[2 * r + 1];
    float4 b0 = on[2 * r], b1 = on[2 * r + 1];
    float4 k2 = make_float4(a0.x + b0.x, a0.y + b0.y, a0.z + b0.z, a0.w + b0.w);
    float4 q2 = make_float4(a1.x + b1.x, a1.y + b1.y, a1.z + b1.z, a1.w + b1.w);
    float4* o4 = (float4*)out;
    const size_t idx = ((size_t)(m * NN + n) * RR + r);
    o4[idx] = k2;
    o4[(size_t)NN * NN * RR + idx] = q2;
}

extern "C" void kernel_launch(void* const* d_in, const int* in_sizes, int n_in,
                              void* d_out, int out_size, void* d_ws, size_t ws_size,
                              hipStream_t stream) {
    const float* x    = (const float*)d_in[0];
    const float* h    = (const float*)d_in[1];
    const float* Wfc  = (const float*)d_in[2];
    const float* Wsum = (const float*)d_in[3];
    const float* bsum = (const float*)d_in[4];
    float* out = (float*)d_out;

    float* hp   = (float*)d_ws;                         // 384*1024 f32 = 1.5 MB
    float* outv = hp + (size_t)NN * HP_W;               // 384*128 f32

    // smearing constants (host-side, double precision)
    double startd = exp(-5.0);
    double rd = (2.0 / 16.0) * (1.0 - startd);
    float beta = (float)(1.0 / (rd * rd));
    float start = (float)startd;

    k_hp<<<NN, 256, 0, stream>>>(h, Wfc, hp);
    k_mid<<<NN, 256, 0, stream>>>(x, hp, Wsum, bsum, outv, beta, start);
    k_expand<<<NN * 24, 256, 0, stream>>>(outv, out);
}

// Round 2
// 70.477 us; speedup vs baseline: 1.5764x; 1.5764x over previous
//
#include <hip/hip_runtime.h>
#include <math.h>

#define NN 384
#define IN_F 64
#define HID 32
#define RR 16
#define HP_W 1024   // 2*R*HID
#define EPSF 1e-5f
#define CHUNK 48
#define NCHUNK 8    // NN / CHUNK
#define MT 2        // m values per block

// ---------------- kernel 1: hp^T[m][kq][c][r] = h @ W_fc^T, stored transposed ----------------
__global__ __launch_bounds__(256) void k_hp(const float* __restrict__ h,
                                            const float* __restrict__ Wfc,
                                            float* __restrict__ hpT) {
    int m = blockIdx.x;
    __shared__ float4 hs4[IN_F / 4];
    int tid = threadIdx.x;
    if (tid < IN_F / 4) hs4[tid] = ((const float4*)(h + m * IN_F))[tid];
    __syncthreads();
    const float4* W4 = (const float4*)Wfc;
    for (int jj = 0; jj < 4; ++jj) {
        int j = tid + 256 * jj;                 // j = kq*512 + r*32 + c
        const float4* row = W4 + (size_t)j * (IN_F / 4);
        float acc = 0.f;
#pragma unroll
        for (int k = 0; k < IN_F / 4; ++k) {
            float4 w = row[k];
            float4 hv = hs4[k];
            acc += w.x * hv.x + w.y * hv.y + w.z * hv.z + w.w * hv.w;
        }
        int kq = j >> 9, rc = j & 511, r = rc >> 5, c = rc & 31;
        hpT[(size_t)m * HP_W + kq * 512 + c * 16 + r] = acc;   // [kq][c][r]
    }
}

// ---------------- kernel 2: partial reduction over an n-chunk for MT m's ----------------
// pbk[m][ch][kq*96+b*32+c] = sum_{n in chunk} dxn[m,n,b] * (sum_r smear[m,n,r]*hpT[n,kq,c,r])
// pS [m][ch][r*3+b]        = sum_{n in chunk} smear[m,n,r]*dxn[m,n,b]
__global__ __launch_bounds__(256) void k_mid(const float* __restrict__ x,
                                             const float* __restrict__ hpT,
                                             float* __restrict__ pbk,
                                             float* __restrict__ pS,
                                             float beta, float start) {
    const int ch = blockIdx.x;
    const int m0 = blockIdx.y * MT;
    const int n0 = ch * CHUNK;
    const int tid = threadIdx.x;

    __shared__ float smear_s[MT][CHUNK][16];   // 6 KB
    __shared__ float dxn_s[MT][CHUNK][3];      // 1.1 KB
    __shared__ float red_s[4][MT][64][3];      // 6 KB

    // phase 1: geometry (MT*CHUNK*16 = 1536 items)
    for (int it = tid; it < MT * CHUNK * 16; it += 256) {
        int mi = it / (CHUNK * 16);
        int rest = it % (CHUNK * 16);
        int np = rest >> 4, r = rest & 15;
        int m = m0 + mi, n = n0 + np;
        float d0 = x[m * 3 + 0] - x[n * 3 + 0];
        float d1 = x[m * 3 + 1] - x[n * 3 + 1];
        float d2 = x[m * 3 + 2] - x[n * 3 + 2];
        float nsq = d0 * d0 + d1 * d1 + d2 * d2 + EPSF;
        float dist = sqrtf(nsq);
        float cut = (dist < 5.0f) ? 0.5f * (__cosf(dist * 0.62831853071795864769f) + 1.0f) : 0.0f;
        float en = __expf(-dist);
        float mean_r = start + (1.0f - start) * ((float)r * (1.0f / 15.0f));
        float dmr = en - mean_r;
        smear_s[mi][np][r] = cut * __expf(-beta * dmr * dmr);
        if (r < 3) dxn_s[mi][np][r] = ((r == 0) ? d0 : ((r == 1) ? d1 : d2)) / nsq;
    }
    __syncthreads();

    // phase 2: thread (g, kq, c); g covers 12 n each; hp read once, used for both m
    const int g = tid >> 6, kq = (tid >> 5) & 1, c = tid & 31;
    float a00 = 0.f, a01 = 0.f, a02 = 0.f, a10 = 0.f, a11 = 0.f, a12 = 0.f;
    const float* hpbase = hpT + (size_t)(n0 + g * 12) * HP_W + kq * 512 + c * 16;
    for (int ni = 0; ni < 12; ++ni) {
        const int np = g * 12 + ni;
        const float4* hp4 = (const float4*)(hpbase + (size_t)ni * HP_W);
        float4 h0 = hp4[0], h1 = hp4[1], h2 = hp4[2], h3 = hp4[3];
        {
            const float4* sm4 = (const float4*)smear_s[0][np];
            float4 s0 = sm4[0], s1 = sm4[1], s2 = sm4[2], s3 = sm4[3];
            float P = h0.x * s0.x + h0.y * s0.y + h0.z * s0.z + h0.w * s0.w
                    + h1.x * s1.x + h1.y * s1.y + h1.z * s1.z + h1.w * s1.w
                    + h2.x * s2.x + h2.y * s2.y + h2.z * s2.z + h2.w * s2.w
                    + h3.x * s3.x + h3.y * s3.y + h3.z * s3.z + h3.w * s3.w;
            a00 += P * dxn_s[0][np][0];
            a01 += P * dxn_s[0][np][1];
            a02 += P * dxn_s[0][np][2];
        }
        {
            const float4* sm4 = (const float4*)smear_s[1][np];
            float4 s0 = sm4[0], s1 = sm4[1], s2 = sm4[2], s3 = sm4[3];
            float P = h0.x * s0.x + h0.y * s0.y + h0.z * s0.z + h0.w * s0.w
                    + h1.x * s1.x + h1.y * s1.y + h1.z * s1.z + h1.w * s1.w
                    + h2.x * s2.x + h2.y * s2.y + h2.z * s2.z + h2.w * s2.w
                    + h3.x * s3.x + h3.y * s3.y + h3.z * s3.z + h3.w * s3.w;
            a10 += P * dxn_s[1][np][0];
            a11 += P * dxn_s[1][np][1];
            a12 += P * dxn_s[1][np][2];
        }
    }
    red_s[g][0][kq * 32 + c][0] = a00;
    red_s[g][0][kq * 32 + c][1] = a01;
    red_s[g][0][kq * 32 + c][2] = a02;
    red_s[g][1][kq * 32 + c][0] = a10;
    red_s[g][1][kq * 32 + c][1] = a11;
    red_s[g][1][kq * 32 + c][2] = a12;

    // S phase (reads only phase-1 LDS; no barrier needed before it)
    float accS = 0.f;
    int smi = 0, ss = 0;
    if (tid < MT * 48) {
        smi = tid / 48; ss = tid % 48;
        const int r = ss / 3, b = ss % 3;
        for (int np = 0; np < CHUNK; ++np)
            accS += smear_s[smi][np][r] * dxn_s[smi][np][b];
    }
    __syncthreads();

    // write partials
    for (int it = tid; it < MT * 192; it += 256) {
        int mi = it / 192, j = it % 192;
        int kq2 = j / 96, b2 = (j % 96) / 32, c2 = j % 32;
        float v = red_s[0][mi][kq2 * 32 + c2][b2] + red_s[1][mi][kq2 * 32 + c2][b2]
                + red_s[2][mi][kq2 * 32 + c2][b2] + red_s[3][mi][kq2 * 32 + c2][b2];
        pbk[((size_t)(m0 + mi) * NCHUNK + ch) * 192 + j] = v;
    }
    if (tid < MT * 48)
        pS[((size_t)(m0 + smi) * NCHUNK + ch) * 48 + ss] = accS;
}

// ---------------- kernel 3: combine partials + epilogue -> outv[m][128] ----------------
__global__ __launch_bounds__(256) void k_combine(const float* __restrict__ hpT,
                                                 const float* __restrict__ Wsum,
                                                 const float* __restrict__ bsum,
                                                 const float* __restrict__ pbk,
                                                 const float* __restrict__ pS,
                                                 float* __restrict__ outv) {
    const int m = blockIdx.x;
    const int tid = threadIdx.x;
    __shared__ float S_s[16][3];
    __shared__ float bkq_s[2][HID][3];
    __shared__ float silu_s[HID];

    float v = 0.f;
    if (tid < 192) {
        for (int chn = 0; chn < NCHUNK; ++chn)
            v += pbk[((size_t)m * NCHUNK + chn) * 192 + tid];
    } else if (tid < 240) {
        int s = tid - 192;
        float a = 0.f;
        for (int chn = 0; chn < NCHUNK; ++chn)
            a += pS[((size_t)m * NCHUNK + chn) * 48 + s];
        S_s[s / 3][s % 3] = a;
    }
    __syncthreads();
    if (tid < 192) {
        const int kq = tid / 96, b = (tid % 96) / 32, cc = tid % 32;
        const float4* hb = (const float4*)(hpT + (size_t)m * HP_W + kq * 512 + cc * 16);
        float4 h0 = hb[0], h1 = hb[1], h2 = hb[2], h3 = hb[3];
        v += h0.x * S_s[0][b] + h0.y * S_s[1][b] + h0.z * S_s[2][b] + h0.w * S_s[3][b]
           + h1.x * S_s[4][b] + h1.y * S_s[5][b] + h1.z * S_s[6][b] + h1.w * S_s[7][b]
           + h2.x * S_s[8][b] + h2.y * S_s[9][b] + h2.z * S_s[10][b] + h2.w * S_s[11][b]
           + h3.x * S_s[12][b] + h3.y * S_s[13][b] + h3.z * S_s[14][b] + h3.w * S_s[15][b];
        bkq_s[kq][cc][b] = v;
    }
    __syncthreads();
    if (tid < HID) {
        float a = bkq_s[0][tid][0] * bkq_s[1][tid][0]
                + bkq_s[0][tid][1] * bkq_s[1][tid][1]
                + bkq_s[0][tid][2] * bkq_s[1][tid][2];
        silu_s[tid] = a / (1.0f + __expf(-a));
    }
    __syncthreads();
    if (tid < 128) {
        float acc = bsum[tid];
        const float* wr = Wsum + tid * HID;
#pragma unroll
        for (int c2 = 0; c2 < HID; ++c2) acc += wr[c2] * silu_s[c2];
        outv[(size_t)m * 128 + tid] = acc;
    }
}

// ---------------- kernel 4: K2/Q2 expansion ----------------
__global__ __launch_bounds__(256) void k_expand(const float* __restrict__ outv,
                                                float* __restrict__ out) {
    const int bid = blockIdx.x;
    const int m = bid / 24;
    const int n0 = (bid % 24) * 16;
    const int tid = threadIdx.x;
    __shared__ float4 om[32];
    if (tid < 32) om[tid] = ((const float4*)(outv + (size_t)m * 128))[tid];
    __syncthreads();
    const int ni = tid >> 4;
    const int r = tid & 15;
    const int n = n0 + ni;
    const float4* on = (const float4*)(outv + (size_t)n * 128);
    float4 a0 = om[2 * r], a1 = om[2 * r + 1];
    float4 b0 = on[2 * r], b1 = on[2 * r + 1];
    float4 k2 = make_float4(a0.x + b0.x, a0.y + b0.y, a0.z + b0.z, a0.w + b0.w);
    float4 q2 = make_float4(a1.x + b1.x, a1.y + b1.y, a1.z + b1.z, a1.w + b1.w);
    float4* o4 = (float4*)out;
    const size_t idx = ((size_t)(m * NN + n) * RR + r);
    o4[idx] = k2;
    o4[(size_t)NN * NN * RR + idx] = q2;
}

extern "C" void kernel_launch(void* const* d_in, const int* in_sizes, int n_in,
                              void* d_out, int out_size, void* d_ws, size_t ws_size,
                              hipStream_t stream) {
    const float* x    = (const float*)d_in[0];
    const float* h    = (const float*)d_in[1];
    const float* Wfc  = (const float*)d_in[2];
    const float* Wsum = (const float*)d_in[3];
    const float* bsum = (const float*)d_in[4];
    float* out = (float*)d_out;

    float* hpT  = (float*)d_ws;                            // 384*1024
    float* outv = hpT + (size_t)NN * HP_W;                 // 384*128
    float* pbk  = outv + (size_t)NN * 128;                 // 384*8*192
    float* pS   = pbk + (size_t)NN * NCHUNK * 192;         // 384*8*48

    double startd = exp(-5.0);
    double rd = (2.0 / 16.0) * (1.0 - startd);
    float beta = (float)(1.0 / (rd * rd));
    float start = (float)startd;

    k_hp<<<NN, 256, 0, stream>>>(h, Wfc, hpT);
    k_mid<<<dim3(NCHUNK, NN / MT), 256, 0, stream>>>(x, hpT, pbk, pS, beta, start);
    k_combine<<<NN, 256, 0, stream>>>(hpT, Wsum, bsum, pbk, pS, outv);
    k_expand<<<NN * 24, 256, 0, stream>>>(outv, out);
}